// Round 5
// baseline (65.980 us; speedup 1.0000x reference)
//
#include <hip/hip_runtime.h>

// out[i] = sum_b sum_t X[b, (i - t) mod D] * Y[b, t],  B=128, D=1024, fp32.
//
// Kernel 1 (cc_partial): grid 1024 = (b=128) x (tslice=8 of 128 t), 512 thr
//   (= 8 waves; exactly 4 blocks/CU -> 32 waves/CU).
//   - X[b,:] staged 2x-replicated in LDS, PADDED layout: logical float4 f
//     stored at phys f + (f>>3) -> lane-stride-2-float4 b128 reads hit all
//     8 bank quads (conflict-free), address math is 2 VALU (vs swizzle 5).
//   - Y: ONE pre-barrier global load per thread (lane l holds Y[t0+(l&31)]);
//     inner loop broadcasts via v_readlane (compile-time lane index).
//     ZERO memory ops besides the X window in the main loop; ~40 VGPR so
//     no spills at the 64-VGPR/8-wave bound.
//   - 8 outputs x 32 t per thread, sliding 16-float register window
//     (2 new b128 per 8 t), 256 FMAs straight-line.
//   - ts-reduce through LDS, then TRANSPOSED partial store ws4[i4][blk]
//     so kernel 2 reads contiguous rows.
// Kernel 2 (cc_reduce): 256 blocks x 256 thr; block j reads ws4 row j
//   (16 KB contiguous), float4 sums, wave butterfly, out4[j].

#define CC_D 1024

__device__ __forceinline__ int padf(int f) { return f + (f >> 3); }

__device__ __forceinline__ float bcast(float v, int lane) {
  return __int_as_float(__builtin_amdgcn_readlane(__float_as_int(v), lane));
}

__global__ __launch_bounds__(512, 8) void cc_partial_kernel(
    const float* __restrict__ X, const float* __restrict__ Y,
    float* __restrict__ ws) {
  const int blk    = blockIdx.x;   // 0..1023
  const int b      = blk >> 3;     // 0..127
  const int tslice = blk & 7;      // 128 t's each
  const int tid    = threadIdx.x;  // 0..511
  const int ig     = tid & 127;    // outputs i = 8*ig .. 8*ig+7
  const int ts     = tid >> 7;     // 0..3: 32-t quarter (uniform per wave)
  const int lane   = tid & 63;

  __shared__ __align__(16) float smem[4096];   // 16 KB; X-pad area 9.2 KB
  float4* sm4 = (float4*)smem;

  const int t0 = tslice * 128 + ts * 32;

  // Issue X staging load and Y lane load together; latency hides under
  // the barrier.
  float4 xv = make_float4(0.f, 0.f, 0.f, 0.f);
  if (tid < 256) xv = ((const float4*)(X + b * CC_D))[tid];
  const float ymine = Y[b * CC_D + t0 + (lane & 31)];

  if (tid < 256) {
    sm4[padf(tid)]       = xv;
    sm4[padf(tid + 256)] = xv;
  }
  __syncthreads();

  // Window group g (t = t0 + 8g + r): W[j] = xlog[4*(f0 - 2g) + j], j=0..15
  // (xlog = unpadded logical floats, base 1024 + 8*ig - t0 - 8 - 8g).
  // acc[q] += W[8+q-r] * y[8g+r].
  const int f0 = 254 + 2 * ig - (t0 >> 2);

  float W[16];
#pragma unroll
  for (int m = 0; m < 4; ++m) {
    const float4 w = sm4[padf(f0 + m)];
    W[4 * m + 0] = w.x; W[4 * m + 1] = w.y;
    W[4 * m + 2] = w.z; W[4 * m + 3] = w.w;
  }

  float acc[8];
#pragma unroll
  for (int q = 0; q < 8; ++q) acc[q] = 0.f;

#pragma unroll
  for (int g = 0; g < 4; ++g) {
#pragma unroll
    for (int r = 0; r < 8; ++r) {
      const float ybc = bcast(ymine, 8 * g + r);  // v_readlane, const lane
#pragma unroll
      for (int q = 0; q < 8; ++q)
        acc[q] += W[8 + q - r] * ybc;
    }

    if (g < 3) {
#pragma unroll
      for (int j = 0; j < 8; ++j) W[8 + j] = W[j];
      const float4 w0 = sm4[padf(f0 - 2 * (g + 1))];
      const float4 w1 = sm4[padf(f0 - 2 * (g + 1) + 1)];
      W[0] = w0.x; W[1] = w0.y; W[2] = w0.z; W[3] = w0.w;
      W[4] = w1.x; W[5] = w1.y; W[6] = w1.z; W[7] = w1.w;
    }
  }

  // In-LDS reduce over the 4 ts quarters.
  __syncthreads();
  float4* st = (float4*)(smem + ts * CC_D + 8 * ig);
  st[0] = make_float4(acc[0], acc[1], acc[2], acc[3]);
  st[1] = make_float4(acc[4], acc[5], acc[6], acc[7]);
  __syncthreads();

  if (tid < 256) {
    float4 s = make_float4(0.f, 0.f, 0.f, 0.f);
#pragma unroll
    for (int sidx = 0; sidx < 4; ++sidx) {
      const float4 v = ((const float4*)smem)[sidx * 256 + tid];
      s.x += v.x; s.y += v.y; s.z += v.z; s.w += v.w;
    }
    // transposed: ws4[i4 = tid][blk] -> kernel 2 reads contiguous rows
    ((float4*)ws)[(size_t)tid * 1024 + blk] = s;
  }
}

__global__ __launch_bounds__(256) void cc_reduce_kernel(
    const float* __restrict__ ws, float* __restrict__ out) {
  const int j   = blockIdx.x;        // outputs 4j..4j+3
  const int tid = threadIdx.x;
  const int l   = tid & 63;
  const int w   = tid >> 6;          // wave 0..3

  __shared__ float4 red[4];

  const float4* row = (const float4*)ws + (size_t)j * 1024;
  float4 s = make_float4(0.f, 0.f, 0.f, 0.f);
#pragma unroll
  for (int c = 0; c < 4; ++c) {
    const float4 v = row[(size_t)(c * 256 + tid)];
    s.x += v.x; s.y += v.y; s.z += v.z; s.w += v.w;
  }
#pragma unroll
  for (int o = 32; o > 0; o >>= 1) {
    s.x += __shfl_xor(s.x, o, 64);
    s.y += __shfl_xor(s.y, o, 64);
    s.z += __shfl_xor(s.z, o, 64);
    s.w += __shfl_xor(s.w, o, 64);
  }
  if (l == 0) red[w] = s;
  __syncthreads();

  if (tid == 0) {
    float4 r = red[0];
    r.x += red[1].x + red[2].x + red[3].x;
    r.y += red[1].y + red[2].y + red[3].y;
    r.z += red[1].z + red[2].z + red[3].z;
    r.w += red[1].w + red[2].w + red[3].w;
    ((float4*)out)[j] = r;
  }
}

extern "C" void kernel_launch(void* const* d_in, const int* in_sizes, int n_in,
                              void* d_out, int out_size, void* d_ws,
                              size_t ws_size, hipStream_t stream) {
  const float* X = (const float*)d_in[0];  // (128, 1024) f32
  const float* Y = (const float*)d_in[1];  // (128, 1024) f32
  float* out = (float*)d_out;              // 1024 f32
  float* ws  = (float*)d_ws;               // 4 MB used

  cc_partial_kernel<<<1024, 512, 0, stream>>>(X, Y, ws);
  cc_reduce_kernel<<<256, 256, 0, stream>>>(ws, out);
}